// Round 5
// baseline (317.800 us; speedup 1.0000x reference)
//
#include <hip/hip_runtime.h>
#include <stdint.h>

// Problem constants (MultiHeadAttention: B=4,T=2048,C=1024,H=16,Dh=64)
#define EMB   1024
#define NH    16
#define DH    64
#define NB    4
#define NT    2048
#define BT    (NB*NT)       // 8192 rows
#define NQKV  (3*EMB)       // 3072
// SCALE * log2(e) = 0.125 * 1.4426950408889634  (folded into Q at QKV epilogue)
#define CL2E  0.1803368801111204f

typedef short v4s __attribute__((ext_vector_type(4)));
typedef short v8s __attribute__((ext_vector_type(8)));
typedef float v4f __attribute__((ext_vector_type(4)));

__device__ __forceinline__ unsigned short f2bf(float f) {
  unsigned int u = __builtin_bit_cast(unsigned int, f);
  u += 0x7fffu + ((u >> 16) & 1u);
  return (unsigned short)(u >> 16);
}

// async global->LDS, 16B per lane (dest = wave-uniform base + lane*16).
__device__ __forceinline__ void gld16(const unsigned short* g, unsigned short* l) {
  __builtin_amdgcn_global_load_lds(
      (const __attribute__((address_space(1))) unsigned int*)g,
      (__attribute__((address_space(3))) unsigned int*)l, 16, 0, 0);
}

// exp2 each of 4 floats, round to bf16 (+0x8000 nearest), pack to v4s.
__device__ __forceinline__ v4s exppack(v4f s) {
  unsigned int u0 = __builtin_bit_cast(unsigned int, exp2f(s[0])) + 0x8000u;
  unsigned int u1 = __builtin_bit_cast(unsigned int, exp2f(s[1])) + 0x8000u;
  unsigned int u2 = __builtin_bit_cast(unsigned int, exp2f(s[2])) + 0x8000u;
  unsigned int u3 = __builtin_bit_cast(unsigned int, exp2f(s[3])) + 0x8000u;
  uint2 d;
  d.x = __builtin_amdgcn_perm(u1, u0, 0x07060302u);
  d.y = __builtin_amdgcn_perm(u3, u2, 0x07060302u);
  return __builtin_bit_cast(v4s, d);
}

// ---------------------------------------------------------------- cast x->bf16
__global__ __launch_bounds__(256) void cast_bf16_k(
    const float* __restrict__ in, unsigned short* __restrict__ out, int n8) {
  int i = blockIdx.x * 256 + threadIdx.x;
  if (i >= n8) return;
  const float4* p = (const float4*)in + (size_t)i * 2;
  float4 a = p[0], b = p[1];
  union { unsigned short s[8]; uint4 u; } o;
  o.s[0] = f2bf(a.x); o.s[1] = f2bf(a.y); o.s[2] = f2bf(a.z); o.s[3] = f2bf(a.w);
  o.s[4] = f2bf(b.x); o.s[5] = f2bf(b.y); o.s[6] = f2bf(b.z); o.s[7] = f2bf(b.w);
  ((uint4*)out)[i] = o.u;
}

// ------------------------------------------- transpose+cast W(R,C)->Wt(C,R) bf16
__global__ __launch_bounds__(256) void transpose_cast_k(
    const float* __restrict__ in, unsigned short* __restrict__ out, int R, int C) {
  __shared__ float tile[32][33];
  int t = threadIdx.x, lr = t >> 5, lc = t & 31;
  int r0 = blockIdx.y * 32, c0 = blockIdx.x * 32;
#pragma unroll
  for (int i = 0; i < 32; i += 8)
    tile[lr + i][lc] = in[(size_t)(r0 + lr + i) * C + c0 + lc];
  __syncthreads();
#pragma unroll
  for (int i = 0; i < 32; i += 8)
    out[(size_t)(c0 + lr + i) * R + r0 + lc] = f2bf(tile[lc][lr + i]);
}

// ---------------------------------------------------------------- GEMM A * B^T
// (unchanged — verified). 128x128 tile, BK=32, XOR-swizzled LDS.
// MODE 0: scatters Q (pre-scaled by CL2E), K (b,h,t,d), V transposed (b,h,d,t).
// MODE 1: writes f32 C (M,N) + bias.
template <int MODE>
__global__ __launch_bounds__(256, 2) void gemm_bt(
    const unsigned short* __restrict__ A, const unsigned short* __restrict__ Bt,
    const float* __restrict__ bias, float* __restrict__ Co,
    unsigned short* __restrict__ q_out, unsigned short* __restrict__ k_out,
    unsigned short* __restrict__ v_out, int M, int N, int K) {
  const int t = threadIdx.x;
  const int wave = t >> 6, lane = t & 63;
  const int m16 = lane & 15, quad = lane >> 4;
  const int wr = wave >> 1, wc = wave & 1;
  const int bm = blockIdx.y * 128, bn = blockIdx.x * 128;

  __shared__ unsigned short As[128 * 32];
  __shared__ unsigned short Bs[128 * 32];

  v4f acc[4][4];
#pragma unroll
  for (int mi = 0; mi < 4; mi++)
#pragma unroll
    for (int ni = 0; ni < 4; ni++) acc[mi][ni] = (v4f){0.f, 0.f, 0.f, 0.f};

  const int sF = (m16 ^ (m16 >> 2)) & 3;

  const int cA = t, rA = cA >> 2, jA = (cA & 3) ^ ((rA ^ (rA >> 2)) & 3);
  const int cB = 256 + t, rB = cB >> 2, jB = (cB & 3) ^ ((rB ^ (rB >> 2)) & 3);
  const unsigned short* gA0 = A + (size_t)(bm + rA) * K + jA * 8;
  const unsigned short* gA1 = A + (size_t)(bm + rB) * K + jB * 8;
  const unsigned short* gB0 = Bt + (size_t)(bn + rA) * K + jA * 8;
  const unsigned short* gB1 = Bt + (size_t)(bn + rB) * K + jB * 8;
  const unsigned short* aBase = &As[(wr * 64 + m16) * 32 + ((quad ^ sF) * 8)];
  const unsigned short* bBase = &Bs[(wc * 64 + m16) * 32 + ((quad ^ sF) * 8)];

  const int nkt = K >> 5;
  for (int kt = 0; kt < nkt; ++kt) {
    gld16(gA0, &As[cA * 8]);
    gld16(gA1, &As[cB * 8]);
    gld16(gB0, &Bs[cA * 8]);
    gld16(gB1, &Bs[cB * 8]);
    gA0 += 32; gA1 += 32; gB0 += 32; gB1 += 32;
    __syncthreads();

    v8s a[4], b[4];
#pragma unroll
    for (int mi = 0; mi < 4; mi++)
      a[mi] = *(const v8s*)(aBase + mi * 16 * 32);
#pragma unroll
    for (int ni = 0; ni < 4; ni++)
      b[ni] = *(const v8s*)(bBase + ni * 16 * 32);
#pragma unroll
    for (int mi = 0; mi < 4; mi++)
#pragma unroll
      for (int ni = 0; ni < 4; ni++)
        acc[mi][ni] = __builtin_amdgcn_mfma_f32_16x16x32_bf16(a[mi], b[ni], acc[mi][ni], 0, 0, 0);
    __syncthreads();
  }

  if (MODE == 0) {
#pragma unroll
    for (int mi = 0; mi < 4; mi++) {
#pragma unroll
      for (int ni = 0; ni < 4; ni++) {
        int col = bn + wc * 64 + ni * 16 + m16;
        int which = col >> 10;
        int h = (col >> 6) & 15, d = col & 63;
        float bv = bias[col];
        float sc = (which == 0) ? CL2E : 1.f;
        int row0 = bm + wr * 64 + mi * 16 + quad * 4;
        int bb = row0 >> 11, tt0 = row0 & 2047;
        float v0 = (acc[mi][ni][0] + bv) * sc, v1 = (acc[mi][ni][1] + bv) * sc;
        float v2 = (acc[mi][ni][2] + bv) * sc, v3 = (acc[mi][ni][3] + bv) * sc;
        if (which == 2) {
          ushort4 pk; pk.x = f2bf(v0); pk.y = f2bf(v1); pk.z = f2bf(v2); pk.w = f2bf(v3);
          *(ushort4*)&v_out[(((size_t)(bb * NH + h)) * DH + d) * NT + tt0] = pk;
        } else {
          unsigned short* dst = (which == 0) ? q_out : k_out;
          size_t idx = (((size_t)(bb * NH + h)) * NT + tt0) * DH + d;
          dst[idx] = f2bf(v0); dst[idx + DH] = f2bf(v1);
          dst[idx + 2 * DH] = f2bf(v2); dst[idx + 3 * DH] = f2bf(v3);
        }
      }
    }
  } else {
#pragma unroll
    for (int mi = 0; mi < 4; mi++) {
#pragma unroll
      for (int ni = 0; ni < 4; ni++) {
        int col = bn + wc * 64 + ni * 16 + m16;
        float bv = bias[col];
#pragma unroll
        for (int r = 0; r < 4; r++) {
          int row = bm + wr * 64 + mi * 16 + quad * 4 + r;
          Co[(size_t)row * N + col] = acc[mi][ni][r] + bv;
        }
      }
    }
  }
}

// ---------------------------------------------------------------- flash attention
// Q (pre-scaled by CL2E),K: (B*H, T, Dh) bf16. Vt: (B*H, Dh, T) bf16.
// Out: (B*T, EMB) bf16.  Block = 4 waves, 256 Q rows (64/wave = 4 tq tiles).
// S^T formulation: St = K*Q^T (16x16x32). C/D layout of St tile == B-operand
// layout of mfma_f32_16x16x16bf16_1k -> exp2+pack in-register, feed straight
// into O^T += V^T * P. K/V LDS fragments shared across all 4 tq streams
// (per-Q-row LDS read traffic halved vs 2-tq version).
// Denominator L via MFMA with ones A-fragment (consistent with bf16 P).
__global__ __launch_bounds__(256, 2) void flash_attn(
    const unsigned short* __restrict__ Qg, const unsigned short* __restrict__ Kg,
    const unsigned short* __restrict__ Vtg, unsigned short* __restrict__ Og) {
  const int t = threadIdx.x;
  const int w = t >> 6, lane = t & 63;
  const int m16 = lane & 15, quad = lane >> 4;
  const int qt = blockIdx.x, bh = blockIdx.y;
  const int b = bh >> 4, h = bh & 15;

  __shared__ unsigned short Ks[128 * 64];     // swizzled [key][d]
  __shared__ unsigned short Vt[64 * 128];     // swizzled [d][key]

  const size_t baseq = (size_t)bh * NT * DH;  // Q,K: (t,d)
  const size_t basev = (size_t)bh * DH * NT;  // Vt:  (d,t)

  // Q fragments: four 16-row tiles (B-operand of the S^T mfma)
  v8s qf[4][2];
#pragma unroll
  for (int tq = 0; tq < 4; tq++) {
    int qrow = qt * 256 + w * 64 + tq * 16 + m16;
#pragma unroll
    for (int kk = 0; kk < 2; kk++)
      qf[tq][kk] = *(const v8s*)&Qg[baseq + (size_t)qrow * DH + kk * 32 + quad * 8];
  }

  v4f accO[4][4], accL[4];
#pragma unroll
  for (int tq = 0; tq < 4; tq++) {
#pragma unroll
    for (int i = 0; i < 4; i++) accO[tq][i] = (v4f){0.f, 0.f, 0.f, 0.f};
    accL[tq] = (v4f){0.f, 0.f, 0.f, 0.f};
  }
  const v4f zero4 = (v4f){0.f, 0.f, 0.f, 0.f};
  const v4s ones4 = (v4s){(short)0x3F80, (short)0x3F80, (short)0x3F80, (short)0x3F80};

  // ---- loop-invariant addresses
  const int sK = m16 & 7;
  const int rK = t >> 3, jK = (t & 7) ^ (rK & 7);
  const int dV = t >> 4, jV = (t & 15) ^ (dV & 15);
  const unsigned short* gK = &Kg[baseq + (size_t)rK * DH + jK * 8];
  const unsigned short* gV = &Vtg[basev + (size_t)dV * NT + jV * 8];
  const unsigned short* kb0 = &Ks[m16 * 64 + (((0 * 4 + quad) ^ sK) * 8)];
  const unsigned short* kb1 = &Ks[m16 * 64 + (((1 * 4 + quad) ^ sK) * 8)];
  const int qh = quad >> 1, q1 = quad & 1;
  const unsigned short* vBase = &Vt[m16 * 128 + q1 * 4];

  for (int kt = 0; kt < NT / 128; ++kt) {
    __syncthreads();  // all waves done reading previous Ks/Vt
#pragma unroll
    for (int i = 0; i < 4; ++i)
      gld16(gK + (size_t)(i * 32) * DH, &Ks[(i * 256 + t) * 8]);
#pragma unroll
    for (int i = 0; i < 4; ++i)
      gld16(gV + (size_t)(i * 16) * NT, &Vt[(i * 256 + t) * 8]);
    gK += 128 * DH;
    gV += 128;
    __syncthreads();

#pragma unroll
    for (int ni = 0; ni < 8; ni++) {
      v8s k0 = *(const v8s*)(kb0 + ni * 1024);
      v8s k1 = *(const v8s*)(kb1 + ni * 1024);
      // S^T tiles for all 4 tq streams -> exp2 -> packed P (in-register)
      v4s pp[4];
#pragma unroll
      for (int tq = 0; tq < 4; tq++) {
        v4f s = __builtin_amdgcn_mfma_f32_16x16x32_bf16(k0, qf[tq][0], zero4, 0, 0, 0);
        s = __builtin_amdgcn_mfma_f32_16x16x32_bf16(k1, qf[tq][1], s, 0, 0, 0);
        pp[tq] = exppack(s);
      }
      // L += 1 * P (matrix pipe, consistent with bf16 P numerator)
#pragma unroll
      for (int tq = 0; tq < 4; tq++)
        accL[tq] = __builtin_amdgcn_mfma_f32_16x16x16bf16_1k(ones4, pp[tq], accL[tq], 0, 0, 0);
      // O^T += V^T * P ; V fragment shared across the 4 tq streams
      const unsigned short* vA = vBase + (((ni * 2 + qh) ^ m16) * 8);
#pragma unroll
      for (int ni2 = 0; ni2 < 4; ni2++) {
        v4s vf = *(const v4s*)(vA + ni2 * 2048);
#pragma unroll
        for (int tq = 0; tq < 4; tq++)
          accO[tq][ni2] = __builtin_amdgcn_mfma_f32_16x16x16bf16_1k(vf, pp[tq], accO[tq][ni2], 0, 0, 0);
      }
    }
  }

  // epilogue: O^T tiles: lane (col=qrow=m16) holds d = ni2*16+quad*4+r.
#pragma unroll
  for (int tq = 0; tq < 4; tq++) {
    float inv = 1.f / accL[tq][0];
    int trow = qt * 256 + w * 64 + tq * 16 + m16;
    size_t ob = ((size_t)b * NT + trow) * EMB + h * DH;
#pragma unroll
    for (int ni2 = 0; ni2 < 4; ni2++) {
      float v0 = accO[tq][ni2][0] * inv, v1 = accO[tq][ni2][1] * inv;
      float v2 = accO[tq][ni2][2] * inv, v3 = accO[tq][ni2][3] * inv;
      uint2 d;
      d.x = (unsigned int)f2bf(v0) | ((unsigned int)f2bf(v1) << 16);
      d.y = (unsigned int)f2bf(v2) | ((unsigned int)f2bf(v3) << 16);
      *(uint2*)&Og[ob + ni2 * 16 + quad * 4] = d;
    }
  }
}

// ---------------------------------------------------------------- launch
extern "C" void kernel_launch(void* const* d_in, const int* in_sizes, int n_in,
                              void* d_out, int out_size, void* d_ws, size_t ws_size,
                              hipStream_t stream) {
  const float* x     = (const float*)d_in[0];
  const float* w_qkv = (const float*)d_in[1];
  const float* b_qkv = (const float*)d_in[2];
  const float* w_out = (const float*)d_in[3];
  const float* b_out = (const float*)d_in[4];
  float* out = (float*)d_out;

  unsigned short* xb    = (unsigned short*)d_ws;            // 8192*1024
  unsigned short* wqkvT = xb    + (size_t)BT * EMB;         // 3072*1024
  unsigned short* woutT = wqkvT + (size_t)NQKV * EMB;       // 1024*1024
  unsigned short* qb    = woutT + (size_t)EMB * EMB;        // (b,h,t,d), pre-scaled
  unsigned short* kb    = qb    + (size_t)NB * NH * NT * DH; // (b,h,t,d)
  unsigned short* vb    = kb    + (size_t)NB * NH * NT * DH; // (b,h,d,t) transposed!
  unsigned short* ao    = vb    + (size_t)NB * NH * NT * DH; // 8192*1024

  cast_bf16_k<<<(BT * EMB / 8 + 255) / 256, 256, 0, stream>>>(x, xb, BT * EMB / 8);
  transpose_cast_k<<<dim3(NQKV / 32, EMB / 32), 256, 0, stream>>>(w_qkv, wqkvT, EMB, NQKV);
  transpose_cast_k<<<dim3(EMB / 32, EMB / 32), 256, 0, stream>>>(w_out, woutT, EMB, EMB);

  gemm_bt<0><<<dim3(NQKV / 128, BT / 128), 256, 0, stream>>>(
      xb, wqkvT, b_qkv, nullptr, qb, kb, vb, BT, NQKV, EMB);

  flash_attn<<<dim3(NT / 256, NB * NH), 256, 0, stream>>>(qb, kb, vb, ao);

  gemm_bt<1><<<dim3(EMB / 128, BT / 128), 256, 0, stream>>>(
      ao, woutT, b_out, out, nullptr, nullptr, nullptr, BT, EMB, EMB);
}

// Round 6
// 309.736 us; speedup vs baseline: 1.0260x; 1.0260x over previous
//
#include <hip/hip_runtime.h>
#include <stdint.h>

// Problem constants (MultiHeadAttention: B=4,T=2048,C=1024,H=16,Dh=64)
#define EMB   1024
#define NH    16
#define DH    64
#define NB    4
#define NT    2048
#define BT    (NB*NT)       // 8192 rows
#define NQKV  (3*EMB)       // 3072
// SCALE * log2(e) = 0.125 * 1.4426950408889634  (folded into Q at QKV epilogue)
#define CL2E  0.1803368801111204f

typedef short v4s __attribute__((ext_vector_type(4)));
typedef short v8s __attribute__((ext_vector_type(8)));
typedef float v4f __attribute__((ext_vector_type(4)));

__device__ __forceinline__ unsigned short f2bf(float f) {
  unsigned int u = __builtin_bit_cast(unsigned int, f);
  u += 0x7fffu + ((u >> 16) & 1u);
  return (unsigned short)(u >> 16);
}

// async global->LDS, 16B per lane (dest = wave-uniform base + lane*16).
__device__ __forceinline__ void gld16(const unsigned short* g, unsigned short* l) {
  __builtin_amdgcn_global_load_lds(
      (const __attribute__((address_space(1))) unsigned int*)g,
      (__attribute__((address_space(3))) unsigned int*)l, 16, 0, 0);
}

// exp2 each of 4 floats, round to bf16 (+0x8000 nearest), pack to v4s.
__device__ __forceinline__ v4s exppack(v4f s) {
  unsigned int u0 = __builtin_bit_cast(unsigned int, exp2f(s[0])) + 0x8000u;
  unsigned int u1 = __builtin_bit_cast(unsigned int, exp2f(s[1])) + 0x8000u;
  unsigned int u2 = __builtin_bit_cast(unsigned int, exp2f(s[2])) + 0x8000u;
  unsigned int u3 = __builtin_bit_cast(unsigned int, exp2f(s[3])) + 0x8000u;
  uint2 d;
  d.x = __builtin_amdgcn_perm(u1, u0, 0x07060302u);
  d.y = __builtin_amdgcn_perm(u3, u2, 0x07060302u);
  return __builtin_bit_cast(v4s, d);
}

// ---------------------------------------------------------------- cast x->bf16
__global__ __launch_bounds__(256) void cast_bf16_k(
    const float* __restrict__ in, unsigned short* __restrict__ out, int n8) {
  int i = blockIdx.x * 256 + threadIdx.x;
  if (i >= n8) return;
  const float4* p = (const float4*)in + (size_t)i * 2;
  float4 a = p[0], b = p[1];
  union { unsigned short s[8]; uint4 u; } o;
  o.s[0] = f2bf(a.x); o.s[1] = f2bf(a.y); o.s[2] = f2bf(a.z); o.s[3] = f2bf(a.w);
  o.s[4] = f2bf(b.x); o.s[5] = f2bf(b.y); o.s[6] = f2bf(b.z); o.s[7] = f2bf(b.w);
  ((uint4*)out)[i] = o.u;
}

// ------------------------------------------- transpose+cast W(R,C)->Wt(C,R) bf16
__global__ __launch_bounds__(256) void transpose_cast_k(
    const float* __restrict__ in, unsigned short* __restrict__ out, int R, int C) {
  __shared__ float tile[32][33];
  int t = threadIdx.x, lr = t >> 5, lc = t & 31;
  int r0 = blockIdx.y * 32, c0 = blockIdx.x * 32;
#pragma unroll
  for (int i = 0; i < 32; i += 8)
    tile[lr + i][lc] = in[(size_t)(r0 + lr + i) * C + c0 + lc];
  __syncthreads();
#pragma unroll
  for (int i = 0; i < 32; i += 8)
    out[(size_t)(c0 + lr + i) * R + r0 + lc] = f2bf(tile[lc][lr + i]);
}

// ---------------------------------------------------------------- GEMM A * B^T
// A: (M,K) bf16 row-major. Bt: (N,K) bf16 row-major. 128x128 tile, BK=64
// (16 K-iters at K=1024: halves barrier/vmcnt-drain events vs BK=32, 32 MFMA
// per barrier). LDS 2x16KB, XOR-swizzle j ^ (row&7) on 8-chunk rows.
// MODE 0: scatters Q (pre-scaled by CL2E), K (b,h,t,d), V transposed (b,h,d,t).
// MODE 1: writes f32 C (M,N) + bias.
template <int MODE>
__global__ __launch_bounds__(256, 2) void gemm_bt(
    const unsigned short* __restrict__ A, const unsigned short* __restrict__ Bt,
    const float* __restrict__ bias, float* __restrict__ Co,
    unsigned short* __restrict__ q_out, unsigned short* __restrict__ k_out,
    unsigned short* __restrict__ v_out, int M, int N, int K) {
  const int t = threadIdx.x;
  const int wave = t >> 6, lane = t & 63;
  const int m16 = lane & 15, quad = lane >> 4;
  const int wr = wave >> 1, wc = wave & 1;
  const int bm = blockIdx.y * 128, bn = blockIdx.x * 128;

  __shared__ unsigned short As[128 * 64];
  __shared__ unsigned short Bs[128 * 64];

  v4f acc[4][4];
#pragma unroll
  for (int mi = 0; mi < 4; mi++)
#pragma unroll
    for (int ni = 0; ni < 4; ni++) acc[mi][ni] = (v4f){0.f, 0.f, 0.f, 0.f};

  // staging: 1024 chunks/tile, 4 per thread. row = c>>3, j = (c&7)^(row&7)
  const unsigned short* gA[4];
  const unsigned short* gB[4];
#pragma unroll
  for (int i = 0; i < 4; ++i) {
    int c = i * 256 + t;
    int row = c >> 3, j = (c & 7) ^ (row & 7);
    gA[i] = A + (size_t)(bm + row) * K + j * 8;
    gB[i] = Bt + (size_t)(bn + row) * K + j * 8;
  }
  // fragment read bases: row = (wr|wc)*64 + mi*16 + m16 (row&7 == m16&7),
  // chunk kk*4+quad, swizzled by m16&7
  const int s7 = m16 & 7;
  const unsigned short* aB0 = &As[(wr * 64 + m16) * 64 + (((0 + quad) ^ s7) * 8)];
  const unsigned short* aB1 = &As[(wr * 64 + m16) * 64 + (((4 + quad) ^ s7) * 8)];
  const unsigned short* bB0 = &Bs[(wc * 64 + m16) * 64 + (((0 + quad) ^ s7) * 8)];
  const unsigned short* bB1 = &Bs[(wc * 64 + m16) * 64 + (((4 + quad) ^ s7) * 8)];

  const int nkt = K >> 6;
  for (int kt = 0; kt < nkt; ++kt) {
#pragma unroll
    for (int i = 0; i < 4; ++i) {
      gld16(gA[i], &As[(i * 256 + t) * 8]);
      gA[i] += 64;
    }
#pragma unroll
    for (int i = 0; i < 4; ++i) {
      gld16(gB[i], &Bs[(i * 256 + t) * 8]);
      gB[i] += 64;
    }
    __syncthreads();   // drains global_load_lds (vmcnt) + protects LDS

#pragma unroll
    for (int kk = 0; kk < 2; kk++) {
      const unsigned short* aB = kk ? aB1 : aB0;
      const unsigned short* bB = kk ? bB1 : bB0;
      v8s a[4], b[4];
#pragma unroll
      for (int mi = 0; mi < 4; mi++)
        a[mi] = *(const v8s*)(aB + mi * 16 * 64);
#pragma unroll
      for (int ni = 0; ni < 4; ni++)
        b[ni] = *(const v8s*)(bB + ni * 16 * 64);
#pragma unroll
      for (int mi = 0; mi < 4; mi++)
#pragma unroll
        for (int ni = 0; ni < 4; ni++)
          acc[mi][ni] = __builtin_amdgcn_mfma_f32_16x16x32_bf16(a[mi], b[ni], acc[mi][ni], 0, 0, 0);
    }
    __syncthreads();   // reads done before next stage overwrites
  }

  if (MODE == 0) {
#pragma unroll
    for (int mi = 0; mi < 4; mi++) {
#pragma unroll
      for (int ni = 0; ni < 4; ni++) {
        int col = bn + wc * 64 + ni * 16 + m16;
        int which = col >> 10;
        int h = (col >> 6) & 15, d = col & 63;
        float bv = bias[col];
        float sc = (which == 0) ? CL2E : 1.f;
        int row0 = bm + wr * 64 + mi * 16 + quad * 4;
        int bb = row0 >> 11, tt0 = row0 & 2047;
        float v0 = (acc[mi][ni][0] + bv) * sc, v1 = (acc[mi][ni][1] + bv) * sc;
        float v2 = (acc[mi][ni][2] + bv) * sc, v3 = (acc[mi][ni][3] + bv) * sc;
        if (which == 2) {
          ushort4 pk; pk.x = f2bf(v0); pk.y = f2bf(v1); pk.z = f2bf(v2); pk.w = f2bf(v3);
          *(ushort4*)&v_out[(((size_t)(bb * NH + h)) * DH + d) * NT + tt0] = pk;
        } else {
          unsigned short* dst = (which == 0) ? q_out : k_out;
          size_t idx = (((size_t)(bb * NH + h)) * NT + tt0) * DH + d;
          dst[idx] = f2bf(v0); dst[idx + DH] = f2bf(v1);
          dst[idx + 2 * DH] = f2bf(v2); dst[idx + 3 * DH] = f2bf(v3);
        }
      }
    }
  } else {
#pragma unroll
    for (int mi = 0; mi < 4; mi++) {
#pragma unroll
      for (int ni = 0; ni < 4; ni++) {
        int col = bn + wc * 64 + ni * 16 + m16;
        float bv = bias[col];
#pragma unroll
        for (int r = 0; r < 4; r++) {
          int row = bm + wr * 64 + mi * 16 + quad * 4 + r;
          Co[(size_t)row * N + col] = acc[mi][ni][r] + bv;
        }
      }
    }
  }
}

// ---------------------------------------------------------------- flash attention
// (R4 configuration — verified 127 us; flash is occupancy/latency-limited, keep
//  3 blocks/CU and 1024 blocks. tq=4 variant regressed: 2 blocks/CU too few.)
// Q (pre-scaled by CL2E),K: (B*H, T, Dh) bf16. Vt: (B*H, Dh, T) bf16.
// Out: (B*T, EMB) bf16.  Block = 4 waves, 128 Q rows (32/wave).
// S^T formulation: St = K*Q^T via 16x16x32. St C/D layout == B-operand layout
// of mfma_f32_16x16x16bf16_1k -> exp2+pack in-register, feed straight into
// O^T += V^T * P. Denominator L via MFMA with ones A-fragment.
__global__ __launch_bounds__(256, 3) void flash_attn(
    const unsigned short* __restrict__ Qg, const unsigned short* __restrict__ Kg,
    const unsigned short* __restrict__ Vtg, unsigned short* __restrict__ Og) {
  const int t = threadIdx.x;
  const int w = t >> 6, lane = t & 63;
  const int m16 = lane & 15, quad = lane >> 4;
  const int qt = blockIdx.x, bh = blockIdx.y;
  const int b = bh >> 4, h = bh & 15;

  __shared__ unsigned short Ks[128 * 64];     // swizzled [key][d]
  __shared__ unsigned short Vt[64 * 128];     // swizzled [d][key]

  const size_t baseq = (size_t)bh * NT * DH;  // Q,K: (t,d)
  const size_t basev = (size_t)bh * DH * NT;  // Vt:  (d,t)

  v8s qf[2][2];
#pragma unroll
  for (int tq = 0; tq < 2; tq++) {
    int qrow = qt * 128 + w * 32 + tq * 16 + m16;
#pragma unroll
    for (int kk = 0; kk < 2; kk++)
      qf[tq][kk] = *(const v8s*)&Qg[baseq + (size_t)qrow * DH + kk * 32 + quad * 8];
  }

  v4f accO[2][4], accL[2];
#pragma unroll
  for (int tq = 0; tq < 2; tq++) {
#pragma unroll
    for (int i = 0; i < 4; i++) accO[tq][i] = (v4f){0.f, 0.f, 0.f, 0.f};
    accL[tq] = (v4f){0.f, 0.f, 0.f, 0.f};
  }
  const v4f zero4 = (v4f){0.f, 0.f, 0.f, 0.f};
  const v4s ones4 = (v4s){(short)0x3F80, (short)0x3F80, (short)0x3F80, (short)0x3F80};

  const int sK = m16 & 7;
  const int rK = t >> 3, jK = (t & 7) ^ (rK & 7);
  const int dV = t >> 4, jV = (t & 15) ^ (dV & 15);
  const unsigned short* gK = &Kg[baseq + (size_t)rK * DH + jK * 8];
  const unsigned short* gV = &Vtg[basev + (size_t)dV * NT + jV * 8];
  const unsigned short* kb0 = &Ks[m16 * 64 + (((0 * 4 + quad) ^ sK) * 8)];
  const unsigned short* kb1 = &Ks[m16 * 64 + (((1 * 4 + quad) ^ sK) * 8)];
  const int qh = quad >> 1, q1 = quad & 1;
  const unsigned short* vBase = &Vt[m16 * 128 + q1 * 4];

  for (int kt = 0; kt < NT / 128; ++kt) {
    __syncthreads();
#pragma unroll
    for (int i = 0; i < 4; ++i)
      gld16(gK + (size_t)(i * 32) * DH, &Ks[(i * 256 + t) * 8]);
#pragma unroll
    for (int i = 0; i < 4; ++i)
      gld16(gV + (size_t)(i * 16) * NT, &Vt[(i * 256 + t) * 8]);
    gK += 128 * DH;
    gV += 128;
    __syncthreads();

    v4s pp[2][8];
#pragma unroll
    for (int ni = 0; ni < 8; ni++) {
      v8s k0 = *(const v8s*)(kb0 + ni * 1024);
      v8s k1 = *(const v8s*)(kb1 + ni * 1024);
      v4f s0 = __builtin_amdgcn_mfma_f32_16x16x32_bf16(k0, qf[0][0], zero4, 0, 0, 0);
      s0 = __builtin_amdgcn_mfma_f32_16x16x32_bf16(k1, qf[0][1], s0, 0, 0, 0);
      v4f s1 = __builtin_amdgcn_mfma_f32_16x16x32_bf16(k0, qf[1][0], zero4, 0, 0, 0);
      s1 = __builtin_amdgcn_mfma_f32_16x16x32_bf16(k1, qf[1][1], s1, 0, 0, 0);
      pp[0][ni] = exppack(s0);
      pp[1][ni] = exppack(s1);
    }

#pragma unroll
    for (int ni = 0; ni < 8; ni++) {
      accL[0] = __builtin_amdgcn_mfma_f32_16x16x16bf16_1k(ones4, pp[0][ni], accL[0], 0, 0, 0);
      accL[1] = __builtin_amdgcn_mfma_f32_16x16x16bf16_1k(ones4, pp[1][ni], accL[1], 0, 0, 0);
      const unsigned short* vA = vBase + (((ni * 2 + qh) ^ m16) * 8);
#pragma unroll
      for (int ni2 = 0; ni2 < 4; ni2++) {
        v4s vf = *(const v4s*)(vA + ni2 * 2048);
        accO[0][ni2] = __builtin_amdgcn_mfma_f32_16x16x16bf16_1k(vf, pp[0][ni], accO[0][ni2], 0, 0, 0);
        accO[1][ni2] = __builtin_amdgcn_mfma_f32_16x16x16bf16_1k(vf, pp[1][ni], accO[1][ni2], 0, 0, 0);
      }
    }
  }

  // epilogue: O^T tiles: lane (col=qrow=m16) holds d = ni2*16+quad*4+r.
#pragma unroll
  for (int tq = 0; tq < 2; tq++) {
    float inv = 1.f / accL[tq][0];
    int trow = qt * 128 + w * 32 + tq * 16 + m16;
    size_t ob = ((size_t)b * NT + trow) * EMB + h * DH;
#pragma unroll
    for (int ni2 = 0; ni2 < 4; ni2++) {
      float v0 = accO[tq][ni2][0] * inv, v1 = accO[tq][ni2][1] * inv;
      float v2 = accO[tq][ni2][2] * inv, v3 = accO[tq][ni2][3] * inv;
      uint2 d;
      d.x = (unsigned int)f2bf(v0) | ((unsigned int)f2bf(v1) << 16);
      d.y = (unsigned int)f2bf(v2) | ((unsigned int)f2bf(v3) << 16);
      *(uint2*)&Og[ob + ni2 * 16 + quad * 4] = d;
    }
  }
}

// ---------------------------------------------------------------- launch
extern "C" void kernel_launch(void* const* d_in, const int* in_sizes, int n_in,
                              void* d_out, int out_size, void* d_ws, size_t ws_size,
                              hipStream_t stream) {
  const float* x     = (const float*)d_in[0];
  const float* w_qkv = (const float*)d_in[1];
  const float* b_qkv = (const float*)d_in[2];
  const float* w_out = (const float*)d_in[3];
  const float* b_out = (const float*)d_in[4];
  float* out = (float*)d_out;

  unsigned short* xb    = (unsigned short*)d_ws;            // 8192*1024
  unsigned short* wqkvT = xb    + (size_t)BT * EMB;         // 3072*1024
  unsigned short* woutT = wqkvT + (size_t)NQKV * EMB;       // 1024*1024
  unsigned short* qb    = woutT + (size_t)EMB * EMB;        // (b,h,t,d), pre-scaled
  unsigned short* kb    = qb    + (size_t)NB * NH * NT * DH; // (b,h,t,d)
  unsigned short* vb    = kb    + (size_t)NB * NH * NT * DH; // (b,h,d,t) transposed!
  unsigned short* ao    = vb    + (size_t)NB * NH * NT * DH; // 8192*1024

  cast_bf16_k<<<(BT * EMB / 8 + 255) / 256, 256, 0, stream>>>(x, xb, BT * EMB / 8);
  transpose_cast_k<<<dim3(NQKV / 32, EMB / 32), 256, 0, stream>>>(w_qkv, wqkvT, EMB, NQKV);
  transpose_cast_k<<<dim3(EMB / 32, EMB / 32), 256, 0, stream>>>(w_out, woutT, EMB, EMB);

  gemm_bt<0><<<dim3(NQKV / 128, BT / 128), 256, 0, stream>>>(
      xb, wqkvT, b_qkv, nullptr, qb, kb, vb, BT, NQKV, EMB);

  flash_attn<<<dim3(NT / 128, NB * NH), 256, 0, stream>>>(qb, kb, vb, ao);

  gemm_bt<1><<<dim3(EMB / 128, BT / 128), 256, 0, stream>>>(
      ao, woutT, b_out, out, nullptr, nullptr, nullptr, BT, EMB, EMB);
}